// Round 2
// baseline (3733.295 us; speedup 1.0000x reference)
//
#include <hip/hip_runtime.h>
#include <cstddef>

// Problem constants (match reference: N=4096, D=2048, B=64)
#define NN 4096
#define DD 2048
#define BB 64

constexpr float kAT     = 0.3f;
constexpr float kDSBETA = 1e-4f;
constexpr float kEB     = 0.5f;
constexpr float kEN     = 0.005f;   // 0.01 * E_B
constexpr float kEPS    = 0.01f;

__device__ __forceinline__ float wave_sum_f(float v) {
#pragma unroll
    for (int o = 32; o; o >>= 1) v += __shfl_xor(v, o, 64);
    return v;
}
__device__ __forceinline__ double wave_sum_d(double v) {
#pragma unroll
    for (int o = 32; o; o >>= 1) v += __shfl_xor(v, o, 64);
    return v;
}
__device__ __forceinline__ float wave_max_f(float v) {
#pragma unroll
    for (int o = 32; o; o >>= 1) v = fmaxf(v, __shfl_xor(v, o, 64));
    return v;
}
__device__ __forceinline__ float wave_min_f(float v) {
#pragma unroll
    for (int o = 32; o; o >>= 1) v = fminf(v, __shfl_xor(v, o, 64));
    return v;
}

// Decide whether `neighbors` arrived as byte-bools or int32.
// int32 little-endian 0/1: every byte at offset %4 != 0 is 0.
// byte-bools at ~50% density: over 64KB the OR is 1 with certainty.
__global__ void detect_nb(const unsigned char* __restrict__ nb, unsigned* __restrict__ flag) {
    unsigned v = 0;
    const int i0 = threadIdx.x * 256;
    for (int i = 0; i < 256; i++) {
        const int idx = i0 + i;
        if ((idx & 3) != 0) v |= nb[idx];
    }
    if (v != 0) atomicOr(flag, 1u);
}

// One block (256 threads) per node row n.
// Phase UPD: apply step-t update to row n if lr(n) > 0 (winner decoded from key_upd).
// Phase ACT: activation of row n vs x_act (fp64 accumulate), atomicMax into key_act.
__global__ __launch_bounds__(256) void som_step(
    const float* __restrict__ x_upd,          // sample for update step (nullptr => no update phase)
    const float* __restrict__ x_act,          // sample for next activation (nullptr => no act phase)
    float* __restrict__ W,                    // N x D (in d_out, in place)
    float* __restrict__ M,                    // N x D (in place)
    float* __restrict__ R,                    // N x D (in place)
    const void* __restrict__ nb,              // N x N, byte-bool or int32 per *flag
    const unsigned* __restrict__ flag,        // 1 = byte-bool, 0 = int32
    const unsigned long long* __restrict__ key_upd,
    unsigned long long* __restrict__ key_act)
{
    const int n   = blockIdx.x;
    const int tid = threadIdx.x;
    __shared__ float  sred[3][4];
    __shared__ double sredd[2][4];

    // ---- learning rate of this row for the update step ----
    float lr = 0.0f;
    if (x_upd != nullptr) {
        const unsigned long long k = *key_upd;
        const double act_w = __longlong_as_double((long long)(k & ~0xFFFULL));
        const int winner   = 4095 - (int)(k & 0xFFFULL);
        if (act_w >= (double)kAT) {                    // do_upd
            if (n == winner) {
                lr = kEB;
            } else {
                const size_t off = (size_t)winner * NN + n;
                const bool isnb = (*flag != 0)
                    ? (((const unsigned char*)nb)[off] != 0)
                    : (((const int*)nb)[off] != 0);
                if (isnb) lr = kEN;
            }
        }
    }
    const bool next = (x_act != nullptr);
    if (lr == 0.0f && !next) return;                   // block-uniform exit

    const size_t rowoff = (size_t)n * DD + (size_t)tid * 8;
    const size_t xoff   = (size_t)tid * 8;
    float w[8], r[8];
    *(float4*)(w)     = *(const float4*)(W + rowoff);
    *(float4*)(w + 4) = *(const float4*)(W + rowoff + 4);

    if (lr != 0.0f) {
        // ---------- update phase ----------
        float m[8], xu[8], mnew[8];
        *(float4*)(m)      = *(const float4*)(M + rowoff);
        *(float4*)(m + 4)  = *(const float4*)(M + rowoff + 4);
        *(float4*)(xu)     = *(const float4*)(x_upd + xoff);
        *(float4*)(xu + 4) = *(const float4*)(x_upd + xoff + 4);

        const float c1 = lr * kDSBETA;
        const float c2 = 1.0f - c1;
        float psum = 0.0f, pmx = -INFINITY, pmn = INFINITY;
#pragma unroll
        for (int j = 0; j < 8; j++) {
            const float d = xu[j] - w[j];
            w[j] = w[j] + lr * d;
            const float mv = c1 * fabsf(d) + c2 * m[j];
            mnew[j] = mv;
            psum += mv;
            pmx = fmaxf(pmx, mv);
            pmn = fminf(pmn, mv);
        }
        psum = wave_sum_f(psum); pmx = wave_max_f(pmx); pmn = wave_min_f(pmn);
        const int wid = tid >> 6, lane = tid & 63;
        if (lane == 0) { sred[0][wid] = psum; sred[1][wid] = pmx; sred[2][wid] = pmn; }
        __syncthreads();
        const float ts  = sred[0][0] + sred[0][1] + sred[0][2] + sred[0][3];
        const float tmx = fmaxf(fmaxf(sred[1][0], sred[1][1]), fmaxf(sred[1][2], sred[1][3]));
        const float tmn = fminf(fminf(sred[2][0], sred[2][1]), fminf(sred[2][2], sred[2][3]));
        __syncthreads();   // sred freed for act phase

        const float av    = ts * (1.0f / (float)DD);
        const float denom = kEPS * (tmx - tmn);
        if (denom == 0.0f) {
#pragma unroll
            for (int j = 0; j < 8; j++) r[j] = 1.0f;
        } else {
#pragma unroll
            for (int j = 0; j < 8; j++) {
                float a = (mnew[j] - av) / denom;
                a = fminf(fmaxf(a, -80.0f), 80.0f);
                r[j] = 1.0f / (1.0f + expf(a));
            }
        }
        *(float4*)(W + rowoff)     = *(float4*)(w);
        *(float4*)(W + rowoff + 4) = *(float4*)(w + 4);
        *(float4*)(M + rowoff)     = *(float4*)(mnew);
        *(float4*)(M + rowoff + 4) = *(float4*)(mnew + 4);
        *(float4*)(R + rowoff)     = *(float4*)(r);
        *(float4*)(R + rowoff + 4) = *(float4*)(r + 4);
    } else {
        // untouched row: R from memory for the act phase
        *(float4*)(r)     = *(const float4*)(R + rowoff);
        *(float4*)(r + 4) = *(const float4*)(R + rowoff + 4);
    }

    if (next) {
        // ---------- activation phase (for step t+1), fp64 accumulate ----------
        float xn[8];
        *(float4*)(xn)     = *(const float4*)(x_act + xoff);
        *(float4*)(xn + 4) = *(const float4*)(x_act + xoff + 4);
        double pd = 0.0, ps = 0.0;
#pragma unroll
        for (int j = 0; j < 8; j++) {
            const double d  = (double)xn[j] - (double)w[j];
            const double rj = (double)r[j];
            pd += rj * d * d;
            ps += rj;
        }
        pd = wave_sum_d(pd); ps = wave_sum_d(ps);
        const int wid = tid >> 6, lane = tid & 63;
        if (lane == 0) { sredd[0][wid] = pd; sredd[1][wid] = ps; }
        __syncthreads();
        if (tid == 0) {
            const double td = sredd[0][0] + sredd[0][1] + sredd[0][2] + sredd[0][3];
            const double tr = sredd[1][0] + sredd[1][1] + sredd[1][2] + sredd[1][3];
            const double act = tr / (tr + td + 1e-7);
            // (act high-52-12 bits | 4095-n): atomicMax == argmax, first-index tie-break
            const unsigned long long ab = (unsigned long long)__double_as_longlong(act);
            const unsigned long long kk = (ab & ~0xFFFULL) | (unsigned long long)(4095 - n);
            atomicMax(key_act, kk);
        }
    }
}

extern "C" void kernel_launch(void* const* d_in, const int* in_sizes, int n_in,
                              void* d_out, int out_size, void* d_ws, size_t ws_size,
                              hipStream_t stream) {
    const float* x  = (const float*)d_in[0];          // B x D
    const float* W0 = (const float*)d_in[1];          // N x D
    float*       M  = (float*)d_in[2];                // N x D (restored each replay)
    float*       R  = (float*)d_in[3];                // N x D (restored each replay)
    const void*  nb = d_in[5];                        // N x N bool (byte or int32)
    float*       W  = (float*)d_out;                  // final weights accumulate here
    unsigned long long* key  = (unsigned long long*)d_ws;           // 64 argmax keys
    unsigned*           flag = (unsigned*)((char*)d_ws + 512);      // nb-encoding flag

    hipMemcpyAsync(W, W0, sizeof(float) * (size_t)NN * DD, hipMemcpyDeviceToDevice, stream);
    hipMemsetAsync(d_ws, 0, 1024, stream);            // keys + flag
    detect_nb<<<1, 256, 0, stream>>>((const unsigned char*)nb, flag);

    // step -1: activation only, for sample 0
    som_step<<<NN, 256, 0, stream>>>(nullptr, x, W, M, R, nb, flag, nullptr, key);

    for (int t = 0; t < BB; t++) {
        const float* xu = x + (size_t)t * DD;
        const float* xa = (t < BB - 1) ? (x + (size_t)(t + 1) * DD) : nullptr;
        unsigned long long* ka = (t < BB - 1) ? (key + t + 1) : nullptr;
        som_step<<<NN, 256, 0, stream>>>(xu, xa, W, M, R, nb, flag, key + t, ka);
    }
}

// Round 3
// 1694.793 us; speedup vs baseline: 2.2028x; 2.2028x over previous
//
#include <hip/hip_runtime.h>
#include <cstddef>

// Problem constants (match reference: N=4096, D=2048, B=64)
#define NN 4096
#define DD 2048
#define BB 64

constexpr float kAT     = 0.3f;
constexpr float kDSBETA = 1e-4f;
constexpr float kEB     = 0.5f;
constexpr float kEN     = 0.005f;   // 0.01 * E_B
constexpr float kEPS    = 0.01f;

__device__ __forceinline__ float wave_sum_f(float v) {
#pragma unroll
    for (int o = 32; o; o >>= 1) v += __shfl_xor(v, o, 64);
    return v;
}
__device__ __forceinline__ double wave_sum_d(double v) {
#pragma unroll
    for (int o = 32; o; o >>= 1) v += __shfl_xor(v, o, 64);
    return v;
}
__device__ __forceinline__ float wave_max_f(float v) {
#pragma unroll
    for (int o = 32; o; o >>= 1) v = fmaxf(v, __shfl_xor(v, o, 64));
    return v;
}
__device__ __forceinline__ float wave_min_f(float v) {
#pragma unroll
    for (int o = 32; o; o >>= 1) v = fminf(v, __shfl_xor(v, o, 64));
    return v;
}
__device__ __forceinline__ unsigned long long wave_max_u64(unsigned long long v) {
#pragma unroll
    for (int o = 32; o; o >>= 1) {
        const unsigned long long u = __shfl_xor(v, o, 64);
        v = (u > v) ? u : v;
    }
    return v;
}

// Decide whether `neighbors` arrived as byte-bools or int32.
__global__ void detect_nb(const unsigned char* __restrict__ nb, unsigned* __restrict__ flag) {
    unsigned v = 0;
    const int i0 = threadIdx.x * 256;
    for (int i = 0; i < 256; i++) {
        const int idx = i0 + i;
        if ((idx & 3) != 0) v |= nb[idx];
    }
    if (v != 0) atomicOr(flag, 1u);
}

// One block (256 threads) per node row n.
// UPD: reduce 64 partial argmax keys (written by previous step) -> winner; apply update.
// ACT: activation vs x_act (fp64), atomicMax into 64 line-padded partial keys.
__global__ __launch_bounds__(256) void som_step(
    const float* __restrict__ x_upd,          // sample for update step (nullptr => no update)
    const float* __restrict__ x_act,          // sample for next activation (nullptr => no act)
    float* __restrict__ W,                    // N x D (in d_out, in place)
    float* __restrict__ M,                    // N x D (in place)
    float* __restrict__ R,                    // N x D (in place)
    const void* __restrict__ nb,              // N x N, byte-bool or int32 per *flag
    const unsigned* __restrict__ flag,        // 1 = byte-bool, 0 = int32
    const unsigned long long* __restrict__ part_upd,  // 64 partial keys (stride-padded)
    unsigned long long* __restrict__ part_act,
    const int stride)                          // elements between partials (8 => 64B lines)
{
    const int n   = blockIdx.x;
    const int tid = threadIdx.x;
    __shared__ float  sred[3][4];
    __shared__ double sredd[2][4];

    // ---- winner decode + learning rate for this row ----
    float lr = 0.0f;
    if (part_upd != nullptr) {
        // each wave reduces the 64 partials independently (no LDS, no barrier)
        unsigned long long k = part_upd[(size_t)(tid & 63) * stride];
        k = wave_max_u64(k);
        const double act_w = __longlong_as_double((long long)(k & ~0xFFFULL));
        const int winner   = 4095 - (int)(k & 0xFFFULL);
        if (act_w >= (double)kAT) {                    // do_upd
            if (n == winner) {
                lr = kEB;
            } else {
                const size_t off = (size_t)winner * NN + n;
                const bool isnb = (*flag != 0)
                    ? (((const unsigned char*)nb)[off] != 0)
                    : (((const int*)nb)[off] != 0);
                if (isnb) lr = kEN;
            }
        }
    }
    const bool next = (x_act != nullptr);
    if (lr == 0.0f && !next) return;                   // block-uniform exit

    const size_t rowoff = (size_t)n * DD + (size_t)tid * 8;
    const size_t xoff   = (size_t)tid * 8;
    float w[8], r[8];
    *(float4*)(w)     = *(const float4*)(W + rowoff);
    *(float4*)(w + 4) = *(const float4*)(W + rowoff + 4);

    if (lr != 0.0f) {
        // ---------- update phase ----------
        float m[8], xu[8], mnew[8];
        *(float4*)(m)      = *(const float4*)(M + rowoff);
        *(float4*)(m + 4)  = *(const float4*)(M + rowoff + 4);
        *(float4*)(xu)     = *(const float4*)(x_upd + xoff);
        *(float4*)(xu + 4) = *(const float4*)(x_upd + xoff + 4);

        const float c1 = lr * kDSBETA;
        const float c2 = 1.0f - c1;
        float psum = 0.0f, pmx = -INFINITY, pmn = INFINITY;
#pragma unroll
        for (int j = 0; j < 8; j++) {
            const float d = xu[j] - w[j];
            w[j] = w[j] + lr * d;
            const float mv = c1 * fabsf(d) + c2 * m[j];
            mnew[j] = mv;
            psum += mv;
            pmx = fmaxf(pmx, mv);
            pmn = fminf(pmn, mv);
        }
        psum = wave_sum_f(psum); pmx = wave_max_f(pmx); pmn = wave_min_f(pmn);
        const int wid = tid >> 6, lane = tid & 63;
        if (lane == 0) { sred[0][wid] = psum; sred[1][wid] = pmx; sred[2][wid] = pmn; }
        __syncthreads();
        const float ts  = sred[0][0] + sred[0][1] + sred[0][2] + sred[0][3];
        const float tmx = fmaxf(fmaxf(sred[1][0], sred[1][1]), fmaxf(sred[1][2], sred[1][3]));
        const float tmn = fminf(fminf(sred[2][0], sred[2][1]), fminf(sred[2][2], sred[2][3]));
        __syncthreads();   // sred freed for act phase

        const float av    = ts * (1.0f / (float)DD);
        const float denom = kEPS * (tmx - tmn);
        if (denom == 0.0f) {
#pragma unroll
            for (int j = 0; j < 8; j++) r[j] = 1.0f;
        } else {
#pragma unroll
            for (int j = 0; j < 8; j++) {
                float a = (mnew[j] - av) / denom;
                a = fminf(fmaxf(a, -80.0f), 80.0f);
                r[j] = 1.0f / (1.0f + expf(a));
            }
        }
        *(float4*)(W + rowoff)     = *(float4*)(w);
        *(float4*)(W + rowoff + 4) = *(float4*)(w + 4);
        *(float4*)(M + rowoff)     = *(float4*)(mnew);
        *(float4*)(M + rowoff + 4) = *(float4*)(mnew + 4);
        *(float4*)(R + rowoff)     = *(float4*)(r);
        *(float4*)(R + rowoff + 4) = *(float4*)(r + 4);
    } else {
        // untouched row: R from memory for the act phase
        *(float4*)(r)     = *(const float4*)(R + rowoff);
        *(float4*)(r + 4) = *(const float4*)(R + rowoff + 4);
    }

    if (next) {
        // ---------- activation phase (for step t+1), fp64 accumulate ----------
        float xn[8];
        *(float4*)(xn)     = *(const float4*)(x_act + xoff);
        *(float4*)(xn + 4) = *(const float4*)(x_act + xoff + 4);
        double pd = 0.0, ps = 0.0;
#pragma unroll
        for (int j = 0; j < 8; j++) {
            const double d  = (double)xn[j] - (double)w[j];
            const double rj = (double)r[j];
            pd += rj * d * d;
            ps += rj;
        }
        pd = wave_sum_d(pd); ps = wave_sum_d(ps);
        const int wid = tid >> 6, lane = tid & 63;
        if (lane == 0) { sredd[0][wid] = pd; sredd[1][wid] = ps; }
        __syncthreads();
        if (tid == 0) {
            const double td = sredd[0][0] + sredd[0][1] + sredd[0][2] + sredd[0][3];
            const double tr = sredd[1][0] + sredd[1][1] + sredd[1][2] + sredd[1][3];
            const double act = tr / (tr + td + 1e-7);
            // (act high bits | 4095-n): max == argmax with first-index tie-break
            const unsigned long long ab = (unsigned long long)__double_as_longlong(act);
            const unsigned long long kk = (ab & ~0xFFFULL) | (unsigned long long)(4095 - n);
            // spread over 64 line-padded partials: ~64 serialized RMW per line instead of 4096
            atomicMax(&part_act[(size_t)(n & 63) * stride], kk);
        }
    }
}

extern "C" void kernel_launch(void* const* d_in, const int* in_sizes, int n_in,
                              void* d_out, int out_size, void* d_ws, size_t ws_size,
                              hipStream_t stream) {
    const float* x  = (const float*)d_in[0];          // B x D
    const float* W0 = (const float*)d_in[1];          // N x D
    float*       M  = (float*)d_in[2];                // N x D (restored each replay)
    float*       R  = (float*)d_in[3];                // N x D (restored each replay)
    const void*  nb = d_in[5];                        // N x N bool (byte or int32)
    float*       W  = (float*)d_out;                  // final weights accumulate here

    // partial-key table: 65 steps x 64 partials, each padded to a 64B line if ws allows
    const int stride = (ws_size >= (size_t)(66 * 64 * 8 * 8 + 64)) ? 8 : 1;
    unsigned long long* part = (unsigned long long*)d_ws;
    const size_t part_bytes = (size_t)65 * 64 * stride * 8;
    unsigned* flagp = (unsigned*)((char*)d_ws + part_bytes);

    hipMemcpyAsync(W, W0, sizeof(float) * (size_t)NN * DD, hipMemcpyDeviceToDevice, stream);
    hipMemsetAsync(d_ws, 0, part_bytes + 64, stream);   // partials + flag
    detect_nb<<<1, 256, 0, stream>>>((const unsigned char*)nb, flagp);

    // step -1: activation only, for sample 0
    som_step<<<NN, 256, 0, stream>>>(nullptr, x, W, M, R, nb, flagp,
                                     nullptr, part, stride);

    for (int t = 0; t < BB; t++) {
        const float* xu = x + (size_t)t * DD;
        const float* xa = (t < BB - 1) ? (x + (size_t)(t + 1) * DD) : nullptr;
        const unsigned long long* pu = part + (size_t)t * 64 * stride;
        unsigned long long*       pa = (t < BB - 1) ? (part + (size_t)(t + 1) * 64 * stride) : nullptr;
        som_step<<<NN, 256, 0, stream>>>(xu, xa, W, M, R, nb, flagp, pu, pa, stride);
    }
}

// Round 5
// 1662.376 us; speedup vs baseline: 2.2458x; 1.0195x over previous
//
#include <hip/hip_runtime.h>
#include <hip/hip_cooperative_groups.h>
#include <cstddef>

namespace cg = cooperative_groups;

// Problem constants (match reference: N=4096, D=2048, B=64)
#define NN 4096
#define DD 2048
#define BB 64
#define RPB 8                 // rows per block (coop kernel)
#define GRID_BLKS (NN / RPB)  // 512 blocks = 2/CU on 256 CUs

constexpr float kAT     = 0.3f;
constexpr float kDSBETA = 1e-4f;
constexpr float kEB     = 0.5f;
constexpr float kEN     = 0.005f;   // 0.01 * E_B
constexpr float kEPS    = 0.01f;

__device__ __forceinline__ float wave_sum_f(float v) {
#pragma unroll
    for (int o = 32; o; o >>= 1) v += __shfl_xor(v, o, 64);
    return v;
}
__device__ __forceinline__ double wave_sum_d(double v) {
#pragma unroll
    for (int o = 32; o; o >>= 1) v += __shfl_xor(v, o, 64);
    return v;
}
__device__ __forceinline__ float wave_max_f(float v) {
#pragma unroll
    for (int o = 32; o; o >>= 1) v = fmaxf(v, __shfl_xor(v, o, 64));
    return v;
}
__device__ __forceinline__ float wave_min_f(float v) {
#pragma unroll
    for (int o = 32; o; o >>= 1) v = fminf(v, __shfl_xor(v, o, 64));
    return v;
}
__device__ __forceinline__ unsigned long long wave_max_u64(unsigned long long v) {
#pragma unroll
    for (int o = 32; o; o >>= 1) {
        const unsigned long long u = __shfl_xor(v, o, 64);
        v = (u > v) ? u : v;
    }
    return v;
}

// Decide whether `neighbors` arrived as byte-bools or int32.
__global__ void detect_nb(const unsigned char* __restrict__ nb, unsigned* __restrict__ flag) {
    unsigned v = 0;
    const int i0 = threadIdx.x * 256;
    for (int i = 0; i < 256; i++) {
        const int idx = i0 + i;
        if ((idx & 3) != 0) v |= nb[idx];
    }
    if (v != 0) atomicOr(flag, 1u);
}

// ---------------------------------------------------------------------------
// Cooperative persistent kernel: all 64 steps in one launch.
// 512 blocks x 256 thr, 8 rows/block; W,R,M all in REGISTERS (no big LDS, so
// runtime occupancy = VGPR-based 2 blocks/CU and the coop check passes).
// ---------------------------------------------------------------------------
__global__ __launch_bounds__(256, 2) void som_all(
    const float* __restrict__ x,            // B x D
    const float* __restrict__ W0,           // N x D initial
    const float* __restrict__ M0,           // N x D initial
    const float* __restrict__ R0,           // N x D initial
    const unsigned char* __restrict__ nbb,  // N x N (byte or int32 per *flag)
    const unsigned* __restrict__ flag,
    float* __restrict__ Wout,               // N x D final (d_out)
    unsigned long long* __restrict__ part)  // BB slots x 64 keys, 64B-padded
{
    cg::grid_group grid = cg::this_grid();
    const int tid  = threadIdx.x;
    const int wid  = tid >> 6;
    const int lane = tid & 63;
    const int n0   = (int)blockIdx.x * RPB;
    const int col  = tid * 8;

    __shared__ double sdd[2][RPB][4];       // act partials [pd|ps][row][wave]
    __shared__ float  sf[3][4];             // upd partials [sum|max|min][wave]
    __shared__ unsigned long long skk[RPB];

    const bool nb_byte = (*flag != 0);
    const int* nbi = (const int*)nbb;

    float w[RPB][8], r[RPB][8], m[RPB][8], xcur[8];

#pragma unroll
    for (int row = 0; row < RPB; ++row) {
        const size_t base = (size_t)(n0 + row) * DD + col;
        *(float4*)(&w[row][0]) = *(const float4*)(W0 + base);
        *(float4*)(&w[row][4]) = *(const float4*)(W0 + base + 4);
        *(float4*)(&r[row][0]) = *(const float4*)(R0 + base);
        *(float4*)(&r[row][4]) = *(const float4*)(R0 + base + 4);
        *(float4*)(&m[row][0]) = *(const float4*)(M0 + base);
        *(float4*)(&m[row][4]) = *(const float4*)(M0 + base + 4);
    }
    *(float4*)(xcur)     = *(const float4*)(x + col);
    *(float4*)(xcur + 4) = *(const float4*)(x + col + 4);

    auto act_phase = [&](int slot) {
#pragma unroll
        for (int row = 0; row < RPB; ++row) {
            double pd = 0.0, ps = 0.0;
#pragma unroll
            for (int j = 0; j < 8; ++j) {
                const double d  = (double)xcur[j] - (double)w[row][j];
                const double rj = (double)r[row][j];
                pd += rj * d * d;
                ps += rj;
            }
            pd = wave_sum_d(pd); ps = wave_sum_d(ps);
            if (lane == 0) { sdd[0][row][wid] = pd; sdd[1][row][wid] = ps; }
        }
        __syncthreads();
        if (tid < RPB) {
            const int row = tid;
            const double td = sdd[0][row][0] + sdd[0][row][1] + sdd[0][row][2] + sdd[0][row][3];
            const double tr = sdd[1][row][0] + sdd[1][row][1] + sdd[1][row][2] + sdd[1][row][3];
            const double act = tr / (tr + td + 1e-7);
            const unsigned long long ab = (unsigned long long)__double_as_longlong(act);
            skk[row] = (ab & ~0xFFFULL) | (unsigned long long)(4095 - (n0 + row));
        }
        __syncthreads();
        if (tid == 0) {
            unsigned long long k = skk[0];
#pragma unroll
            for (int i = 1; i < RPB; ++i) k = (skk[i] > k) ? skk[i] : k;
            atomicMax(&part[(size_t)slot * 64 * 8 + (size_t)(blockIdx.x & 63) * 8], k);
        }
    };

    act_phase(0);

    for (int t = 0; t < BB; ++t) {
        grid.sync();    // slot-t partials complete & visible

        unsigned long long k = __hip_atomic_load(
            &part[(size_t)t * 64 * 8 + (size_t)lane * 8],
            __ATOMIC_RELAXED, __HIP_MEMORY_SCOPE_AGENT);
        k = wave_max_u64(k);
        const double act_w = __longlong_as_double((long long)(k & ~0xFFFULL));
        const int winner   = 4095 - (int)(k & 0xFFFULL);

        if (act_w >= (double)kAT) {     // do_upd (grid-uniform)
#pragma unroll
            for (int row = 0; row < RPB; ++row) {
                const int n = n0 + row;
                float lr = 0.0f;
                if (n == winner) {
                    lr = kEB;
                } else {
                    const size_t off = (size_t)winner * NN + n;
                    const bool isnb = nb_byte ? (nbb[off] != 0) : (nbi[off] != 0);
                    if (isnb) lr = kEN;
                }
                if (lr != 0.0f) {       // block-uniform per row
                    const float c1 = lr * kDSBETA;
                    const float c2 = 1.0f - c1;
                    float psum = 0.0f, pmx = -INFINITY, pmn = INFINITY;
#pragma unroll
                    for (int j = 0; j < 8; ++j) {
                        const float d  = xcur[j] - w[row][j];
                        const float mv = c1 * fabsf(d) + c2 * m[row][j];
                        w[row][j] += lr * d;
                        m[row][j] = mv;
                        psum += mv;
                        pmx = fmaxf(pmx, mv);
                        pmn = fminf(pmn, mv);
                    }
                    psum = wave_sum_f(psum); pmx = wave_max_f(pmx); pmn = wave_min_f(pmn);
                    if (lane == 0) { sf[0][wid] = psum; sf[1][wid] = pmx; sf[2][wid] = pmn; }
                    __syncthreads();
                    const float ts  = sf[0][0] + sf[0][1] + sf[0][2] + sf[0][3];
                    const float tmx = fmaxf(fmaxf(sf[1][0], sf[1][1]), fmaxf(sf[1][2], sf[1][3]));
                    const float tmn = fminf(fminf(sf[2][0], sf[2][1]), fminf(sf[2][2], sf[2][3]));
                    __syncthreads();
                    const float av    = ts * (1.0f / (float)DD);
                    const float denom = kEPS * (tmx - tmn);
                    if (denom == 0.0f) {
#pragma unroll
                        for (int j = 0; j < 8; ++j) r[row][j] = 1.0f;
                    } else {
#pragma unroll
                        for (int j = 0; j < 8; ++j) {
                            float a = (m[row][j] - av) / denom;
                            a = fminf(fmaxf(a, -80.0f), 80.0f);
                            r[row][j] = 1.0f / (1.0f + expf(a));
                        }
                    }
                }
            }
        }

        if (t < BB - 1) {
            const size_t xb = (size_t)(t + 1) * DD + col;
            *(float4*)(xcur)     = *(const float4*)(x + xb);
            *(float4*)(xcur + 4) = *(const float4*)(x + xb + 4);
            act_phase(t + 1);
        }
    }

#pragma unroll
    for (int row = 0; row < RPB; ++row) {
        const size_t base = (size_t)(n0 + row) * DD + col;
        *(float4*)(Wout + base)     = *(float4*)(&w[row][0]);
        *(float4*)(Wout + base + 4) = *(float4*)(&w[row][4]);
    }
}

// ---------------------------------------------------------------------------
// Fallback: the proven round-3 per-step kernel (65 dispatches, 1695 us).
// ---------------------------------------------------------------------------
__global__ __launch_bounds__(256) void som_step(
    const float* __restrict__ x_upd, const float* __restrict__ x_act,
    float* __restrict__ W, float* __restrict__ M, float* __restrict__ R,
    const void* __restrict__ nb, const unsigned* __restrict__ flag,
    const unsigned long long* __restrict__ part_upd,
    unsigned long long* __restrict__ part_act)
{
    const int n   = blockIdx.x;
    const int tid = threadIdx.x;
    __shared__ float  sred[3][4];
    __shared__ double sredd[2][4];

    float lr = 0.0f;
    if (part_upd != nullptr) {
        unsigned long long k = part_upd[(size_t)(tid & 63) * 8];
        k = wave_max_u64(k);
        const double act_w = __longlong_as_double((long long)(k & ~0xFFFULL));
        const int winner   = 4095 - (int)(k & 0xFFFULL);
        if (act_w >= (double)kAT) {
            if (n == winner) lr = kEB;
            else {
                const size_t off = (size_t)winner * NN + n;
                const bool isnb = (*flag != 0)
                    ? (((const unsigned char*)nb)[off] != 0)
                    : (((const int*)nb)[off] != 0);
                if (isnb) lr = kEN;
            }
        }
    }
    const bool next = (x_act != nullptr);
    if (lr == 0.0f && !next) return;

    const size_t rowoff = (size_t)n * DD + (size_t)tid * 8;
    const size_t xoff   = (size_t)tid * 8;
    float w[8], r[8];
    *(float4*)(w)     = *(const float4*)(W + rowoff);
    *(float4*)(w + 4) = *(const float4*)(W + rowoff + 4);

    if (lr != 0.0f) {
        float m[8], xu[8], mnew[8];
        *(float4*)(m)      = *(const float4*)(M + rowoff);
        *(float4*)(m + 4)  = *(const float4*)(M + rowoff + 4);
        *(float4*)(xu)     = *(const float4*)(x_upd + xoff);
        *(float4*)(xu + 4) = *(const float4*)(x_upd + xoff + 4);
        const float c1 = lr * kDSBETA, c2 = 1.0f - c1;
        float psum = 0.0f, pmx = -INFINITY, pmn = INFINITY;
#pragma unroll
        for (int j = 0; j < 8; j++) {
            const float d = xu[j] - w[j];
            w[j] += lr * d;
            const float mv = c1 * fabsf(d) + c2 * m[j];
            mnew[j] = mv; psum += mv;
            pmx = fmaxf(pmx, mv); pmn = fminf(pmn, mv);
        }
        psum = wave_sum_f(psum); pmx = wave_max_f(pmx); pmn = wave_min_f(pmn);
        const int wid = tid >> 6, lane = tid & 63;
        if (lane == 0) { sred[0][wid] = psum; sred[1][wid] = pmx; sred[2][wid] = pmn; }
        __syncthreads();
        const float ts  = sred[0][0] + sred[0][1] + sred[0][2] + sred[0][3];
        const float tmx = fmaxf(fmaxf(sred[1][0], sred[1][1]), fmaxf(sred[1][2], sred[1][3]));
        const float tmn = fminf(fminf(sred[2][0], sred[2][1]), fminf(sred[2][2], sred[2][3]));
        __syncthreads();
        const float av = ts * (1.0f / (float)DD);
        const float denom = kEPS * (tmx - tmn);
        if (denom == 0.0f) {
#pragma unroll
            for (int j = 0; j < 8; j++) r[j] = 1.0f;
        } else {
#pragma unroll
            for (int j = 0; j < 8; j++) {
                float a = (mnew[j] - av) / denom;
                a = fminf(fmaxf(a, -80.0f), 80.0f);
                r[j] = 1.0f / (1.0f + expf(a));
            }
        }
        *(float4*)(W + rowoff)     = *(float4*)(w);
        *(float4*)(W + rowoff + 4) = *(float4*)(w + 4);
        *(float4*)(M + rowoff)     = *(float4*)(mnew);
        *(float4*)(M + rowoff + 4) = *(float4*)(mnew + 4);
        *(float4*)(R + rowoff)     = *(float4*)(r);
        *(float4*)(R + rowoff + 4) = *(float4*)(r + 4);
    } else {
        *(float4*)(r)     = *(const float4*)(R + rowoff);
        *(float4*)(r + 4) = *(const float4*)(R + rowoff + 4);
    }

    if (next) {
        float xn[8];
        *(float4*)(xn)     = *(const float4*)(x_act + xoff);
        *(float4*)(xn + 4) = *(const float4*)(x_act + xoff + 4);
        double pd = 0.0, ps = 0.0;
#pragma unroll
        for (int j = 0; j < 8; j++) {
            const double d  = (double)xn[j] - (double)w[j];
            const double rj = (double)r[j];
            pd += rj * d * d; ps += rj;
        }
        pd = wave_sum_d(pd); ps = wave_sum_d(ps);
        const int wid = tid >> 6, lane = tid & 63;
        if (lane == 0) { sredd[0][wid] = pd; sredd[1][wid] = ps; }
        __syncthreads();
        if (tid == 0) {
            const double td = sredd[0][0] + sredd[0][1] + sredd[0][2] + sredd[0][3];
            const double tr = sredd[1][0] + sredd[1][1] + sredd[1][2] + sredd[1][3];
            const double act = tr / (tr + td + 1e-7);
            const unsigned long long ab = (unsigned long long)__double_as_longlong(act);
            const unsigned long long kk = (ab & ~0xFFFULL) | (unsigned long long)(4095 - n);
            atomicMax(&part_act[(size_t)(n & 63) * 8], kk);
        }
    }
}

extern "C" void kernel_launch(void* const* d_in, const int* in_sizes, int n_in,
                              void* d_out, int out_size, void* d_ws, size_t ws_size,
                              hipStream_t stream) {
    const float*         x   = (const float*)d_in[0];
    const float*         W0  = (const float*)d_in[1];
    float*               M   = (float*)d_in[2];
    float*               R   = (float*)d_in[3];
    const unsigned char* nbb = (const unsigned char*)d_in[5];
    float*               W   = (float*)d_out;

    unsigned long long* part = (unsigned long long*)d_ws;      // 66 slots x 64 x 8 u64
    const size_t part_bytes  = (size_t)66 * 64 * 8 * sizeof(unsigned long long);
    unsigned*           flagp = (unsigned*)((char*)d_ws + part_bytes);

    hipMemsetAsync(d_ws, 0, part_bytes + 64, stream);
    detect_nb<<<1, 256, 0, stream>>>(nbb, flagp);

    // Host-side occupancy check (capture-safe): coop path needs 2 blocks/CU.
    int occ = 0;
    hipError_t qerr = hipOccupancyMaxActiveBlocksPerMultiprocessor(
        &occ, (const void*)som_all, 256, 0);
    bool coop_ok = (qerr == hipSuccess && occ >= 2);

    if (coop_ok) {
        const float* xp = x; const float* w0p = W0; const float* m0p = (const float*)M;
        const float* r0p = (const float*)R; const unsigned char* nbp = nbb;
        const unsigned* fp = flagp; float* wp = W; unsigned long long* pp = part;
        void* args[] = { &xp, &w0p, &m0p, &r0p, &nbp, &fp, &wp, &pp };
        hipError_t lerr = hipLaunchCooperativeKernel((const void*)som_all,
                                                     dim3(GRID_BLKS), dim3(256),
                                                     args, 0, stream);
        if (lerr == hipSuccess) return;
    }

    // ---- fallback: proven 65-dispatch path ----
    hipMemcpyAsync(W, W0, sizeof(float) * (size_t)NN * DD, hipMemcpyDeviceToDevice, stream);
    som_step<<<NN, 256, 0, stream>>>(nullptr, x, W, M, R, nbb, flagp, nullptr, part);
    for (int t = 0; t < BB; t++) {
        const float* xu = x + (size_t)t * DD;
        const float* xa = (t < BB - 1) ? (x + (size_t)(t + 1) * DD) : nullptr;
        const unsigned long long* pu = part + (size_t)t * 64 * 8;
        unsigned long long*       pa = (t < BB - 1) ? (part + (size_t)(t + 1) * 64 * 8) : nullptr;
        som_step<<<NN, 256, 0, stream>>>(xu, xa, W, M, R, nbb, flagp, pu, pa);
    }
}

// Round 6
// 1660.393 us; speedup vs baseline: 2.2484x; 1.0012x over previous
//
#include <hip/hip_runtime.h>
#include <cstddef>

// Problem constants (match reference: N=4096, D=2048, B=64)
#define NN 4096
#define DD 2048
#define BB 64
#define RPB 8                   // rows per block (persistent kernel)
#define NBLK (NN / RPB)         // 512 blocks = 2/CU on 256 CUs (co-resident)

constexpr float kAT     = 0.3f;
constexpr float kDSBETA = 1e-4f;
constexpr float kEB     = 0.5f;
constexpr float kEN     = 0.005f;   // 0.01 * E_B
constexpr float kEPS    = 0.01f;

__device__ __forceinline__ float wave_sum_f(float v) {
#pragma unroll
    for (int o = 32; o; o >>= 1) v += __shfl_xor(v, o, 64);
    return v;
}
__device__ __forceinline__ double wave_sum_d(double v) {
#pragma unroll
    for (int o = 32; o; o >>= 1) v += __shfl_xor(v, o, 64);
    return v;
}
__device__ __forceinline__ float wave_max_f(float v) {
#pragma unroll
    for (int o = 32; o; o >>= 1) v = fmaxf(v, __shfl_xor(v, o, 64));
    return v;
}
__device__ __forceinline__ float wave_min_f(float v) {
#pragma unroll
    for (int o = 32; o; o >>= 1) v = fminf(v, __shfl_xor(v, o, 64));
    return v;
}
__device__ __forceinline__ unsigned long long wave_max_u64(unsigned long long v) {
#pragma unroll
    for (int o = 32; o; o >>= 1) {
        const unsigned long long u = __shfl_xor(v, o, 64);
        v = (u > v) ? u : v;
    }
    return v;
}

// Decide whether `neighbors` arrived as byte-bools or int32.
__global__ void detect_nb(const unsigned char* __restrict__ nb, unsigned* __restrict__ flag) {
    unsigned v = 0;
    const int i0 = threadIdx.x * 256;
    for (int i = 0; i < 256; i++) {
        const int idx = i0 + i;
        if ((idx & 3) != 0) v |= nb[idx];
    }
    if (v != 0) atomicOr(flag, 1u);
}

// ---------------------------------------------------------------------------
// Persistent kernel, PLAIN launch (graph-capturable). All 64 steps in one
// dispatch. 512 blocks x 256 thr, 8 rows/block, W/R/M in registers (+AGPRs).
// Cross-block sync per step = one-way arrival counters (slots are write-once,
// so no WAR edge -> no full barrier, no grid.sync, no L2-flush protocol).
// ---------------------------------------------------------------------------
__global__ __launch_bounds__(256, 2) void som_persist(
    const float* __restrict__ x,            // B x D
    const float* __restrict__ W0,           // N x D initial
    const float* __restrict__ M0,           // N x D initial
    const float* __restrict__ R0,           // N x D initial
    const unsigned char* __restrict__ nbb,  // N x N (byte or int32 per *flag)
    const unsigned* __restrict__ flag,
    float* __restrict__ Wout,               // N x D final (d_out)
    unsigned long long* __restrict__ part,  // BB slots x 64 keys, 64B-padded
    unsigned* __restrict__ cnt)             // BB slots x 8 sub-counters, 64B-padded
{
    const int tid  = threadIdx.x;
    const int wid  = tid >> 6;
    const int lane = tid & 63;
    const int n0   = (int)blockIdx.x * RPB;
    const int col  = tid * 8;

    __shared__ double sdd[2][RPB][4];
    __shared__ float  sf[3][4];
    __shared__ unsigned long long skk[RPB];
    __shared__ unsigned long long sKey;

    const bool nb_byte = (*flag != 0);
    const int* nbi = (const int*)nbb;

    float w[RPB][8], r[RPB][8], m[RPB][8], xcur[8];

#pragma unroll
    for (int row = 0; row < RPB; ++row) {
        const size_t base = (size_t)(n0 + row) * DD + col;
        *(float4*)(&w[row][0]) = *(const float4*)(W0 + base);
        *(float4*)(&w[row][4]) = *(const float4*)(W0 + base + 4);
        *(float4*)(&r[row][0]) = *(const float4*)(R0 + base);
        *(float4*)(&r[row][4]) = *(const float4*)(R0 + base + 4);
        *(float4*)(&m[row][0]) = *(const float4*)(M0 + base);
        *(float4*)(&m[row][4]) = *(const float4*)(M0 + base + 4);
    }
    *(float4*)(xcur)     = *(const float4*)(x + col);
    *(float4*)(xcur + 4) = *(const float4*)(x + col + 4);

    // activation of this block's rows vs xcur -> partial key + arrival for slot
    auto act_phase = [&](int slot) {
#pragma unroll
        for (int row = 0; row < RPB; ++row) {
            double pd = 0.0, ps = 0.0;
#pragma unroll
            for (int j = 0; j < 8; ++j) {
                const double d  = (double)xcur[j] - (double)w[row][j];
                const double rj = (double)r[row][j];
                pd += rj * d * d;
                ps += rj;
            }
            pd = wave_sum_d(pd); ps = wave_sum_d(ps);
            if (lane == 0) { sdd[0][row][wid] = pd; sdd[1][row][wid] = ps; }
        }
        __syncthreads();
        if (tid < RPB) {
            const int row = tid;
            const double td = sdd[0][row][0] + sdd[0][row][1] + sdd[0][row][2] + sdd[0][row][3];
            const double tr = sdd[1][row][0] + sdd[1][row][1] + sdd[1][row][2] + sdd[1][row][3];
            const double act = tr / (tr + td + 1e-7);
            const unsigned long long ab = (unsigned long long)__double_as_longlong(act);
            skk[row] = (ab & ~0xFFFULL) | (unsigned long long)(4095 - (n0 + row));
        }
        __syncthreads();
        if (tid == 0) {
            unsigned long long k = skk[0];
#pragma unroll
            for (int i = 1; i < RPB; ++i) k = (skk[i] > k) ? skk[i] : k;
            atomicMax(&part[((size_t)slot * 64 + (blockIdx.x & 63)) * 8], k);
            // arrival: RELEASE so our atomicMax is visible before the count
            __hip_atomic_fetch_add(&cnt[((size_t)slot * 8 + (blockIdx.x & 7)) * 16], 1u,
                                   __ATOMIC_RELEASE, __HIP_MEMORY_SCOPE_AGENT);
        }
        __syncthreads();
    };

    act_phase(0);

    for (int t = 0; t < BB; ++t) {
        // ---- wait for all 512 slot-t arrivals, then decode winner (wave 0) ----
        if (wid == 0) {
            int it = 0;
            while (true) {
                unsigned c = 0;
                if (lane < 8)
                    c = __hip_atomic_load(&cnt[((size_t)t * 8 + lane) * 16],
                                          __ATOMIC_ACQUIRE, __HIP_MEMORY_SCOPE_AGENT);
                c += __shfl_xor(c, 1, 64);
                c += __shfl_xor(c, 2, 64);
                c += __shfl_xor(c, 4, 64);
                c = __shfl(c, 0, 64);
                if (c >= (unsigned)NBLK) break;
                if (++it > 2000000) break;              // safety valve: fail, don't hang
                __builtin_amdgcn_s_sleep(2);
            }
            unsigned long long k = __hip_atomic_load(
                &part[((size_t)t * 64 + lane) * 8],
                __ATOMIC_RELAXED, __HIP_MEMORY_SCOPE_AGENT);
            k = wave_max_u64(k);
            if (lane == 0) sKey = k;
        }
        __syncthreads();
        const unsigned long long k = sKey;
        __syncthreads();
        const double act_w = __longlong_as_double((long long)(k & ~0xFFFULL));
        const int winner   = 4095 - (int)(k & 0xFFFULL);

        if (act_w >= (double)kAT) {     // do_upd (grid-uniform)
#pragma unroll
            for (int row = 0; row < RPB; ++row) {
                const int n = n0 + row;
                float lr = 0.0f;
                if (n == winner) {
                    lr = kEB;
                } else {
                    const size_t off = (size_t)winner * NN + n;
                    const bool isnb = nb_byte ? (nbb[off] != 0) : (nbi[off] != 0);
                    if (isnb) lr = kEN;
                }
                if (lr != 0.0f) {       // block-uniform per row
                    const float c1 = lr * kDSBETA;
                    const float c2 = 1.0f - c1;
                    float psum = 0.0f, pmx = -INFINITY, pmn = INFINITY;
#pragma unroll
                    for (int j = 0; j < 8; ++j) {
                        const float d  = xcur[j] - w[row][j];
                        const float mv = c1 * fabsf(d) + c2 * m[row][j];
                        w[row][j] += lr * d;
                        m[row][j] = mv;
                        psum += mv;
                        pmx = fmaxf(pmx, mv);
                        pmn = fminf(pmn, mv);
                    }
                    psum = wave_sum_f(psum); pmx = wave_max_f(pmx); pmn = wave_min_f(pmn);
                    if (lane == 0) { sf[0][wid] = psum; sf[1][wid] = pmx; sf[2][wid] = pmn; }
                    __syncthreads();
                    const float ts  = sf[0][0] + sf[0][1] + sf[0][2] + sf[0][3];
                    const float tmx = fmaxf(fmaxf(sf[1][0], sf[1][1]), fmaxf(sf[1][2], sf[1][3]));
                    const float tmn = fminf(fminf(sf[2][0], sf[2][1]), fminf(sf[2][2], sf[2][3]));
                    __syncthreads();
                    const float av    = ts * (1.0f / (float)DD);
                    const float denom = kEPS * (tmx - tmn);
                    if (denom == 0.0f) {
#pragma unroll
                        for (int j = 0; j < 8; ++j) r[row][j] = 1.0f;
                    } else {
#pragma unroll
                        for (int j = 0; j < 8; ++j) {
                            float a = (m[row][j] - av) / denom;
                            a = fminf(fmaxf(a, -80.0f), 80.0f);
                            r[row][j] = 1.0f / (1.0f + expf(a));
                        }
                    }
                }
            }
        }

        if (t < BB - 1) {
            const size_t xb = (size_t)(t + 1) * DD + col;
            *(float4*)(xcur)     = *(const float4*)(x + xb);
            *(float4*)(xcur + 4) = *(const float4*)(x + xb + 4);
            act_phase(t + 1);
        }
    }

#pragma unroll
    for (int row = 0; row < RPB; ++row) {
        const size_t base = (size_t)(n0 + row) * DD + col;
        *(float4*)(Wout + base)     = *(float4*)(&w[row][0]);
        *(float4*)(Wout + base + 4) = *(float4*)(&w[row][4]);
    }
}

// ---------------------------------------------------------------------------
// Fallback: proven round-3 per-step kernel (65 dispatches, ~1.7 ms).
// ---------------------------------------------------------------------------
__global__ __launch_bounds__(256) void som_step(
    const float* __restrict__ x_upd, const float* __restrict__ x_act,
    float* __restrict__ W, float* __restrict__ M, float* __restrict__ R,
    const void* __restrict__ nb, const unsigned* __restrict__ flag,
    const unsigned long long* __restrict__ part_upd,
    unsigned long long* __restrict__ part_act)
{
    const int n   = blockIdx.x;
    const int tid = threadIdx.x;
    __shared__ float  sred[3][4];
    __shared__ double sredd[2][4];

    float lr = 0.0f;
    if (part_upd != nullptr) {
        unsigned long long k = part_upd[(size_t)(tid & 63) * 8];
        k = wave_max_u64(k);
        const double act_w = __longlong_as_double((long long)(k & ~0xFFFULL));
        const int winner   = 4095 - (int)(k & 0xFFFULL);
        if (act_w >= (double)kAT) {
            if (n == winner) lr = kEB;
            else {
                const size_t off = (size_t)winner * NN + n;
                const bool isnb = (*flag != 0)
                    ? (((const unsigned char*)nb)[off] != 0)
                    : (((const int*)nb)[off] != 0);
                if (isnb) lr = kEN;
            }
        }
    }
    const bool next = (x_act != nullptr);
    if (lr == 0.0f && !next) return;

    const size_t rowoff = (size_t)n * DD + (size_t)tid * 8;
    const size_t xoff   = (size_t)tid * 8;
    float w[8], r[8];
    *(float4*)(w)     = *(const float4*)(W + rowoff);
    *(float4*)(w + 4) = *(const float4*)(W + rowoff + 4);

    if (lr != 0.0f) {
        float m[8], xu[8], mnew[8];
        *(float4*)(m)      = *(const float4*)(M + rowoff);
        *(float4*)(m + 4)  = *(const float4*)(M + rowoff + 4);
        *(float4*)(xu)     = *(const float4*)(x_upd + xoff);
        *(float4*)(xu + 4) = *(const float4*)(x_upd + xoff + 4);
        const float c1 = lr * kDSBETA, c2 = 1.0f - c1;
        float psum = 0.0f, pmx = -INFINITY, pmn = INFINITY;
#pragma unroll
        for (int j = 0; j < 8; j++) {
            const float d = xu[j] - w[j];
            w[j] += lr * d;
            const float mv = c1 * fabsf(d) + c2 * m[j];
            mnew[j] = mv; psum += mv;
            pmx = fmaxf(pmx, mv); pmn = fminf(pmn, mv);
        }
        psum = wave_sum_f(psum); pmx = wave_max_f(pmx); pmn = wave_min_f(pmn);
        const int wid = tid >> 6, lane = tid & 63;
        if (lane == 0) { sred[0][wid] = psum; sred[1][wid] = pmx; sred[2][wid] = pmn; }
        __syncthreads();
        const float ts  = sred[0][0] + sred[0][1] + sred[0][2] + sred[0][3];
        const float tmx = fmaxf(fmaxf(sred[1][0], sred[1][1]), fmaxf(sred[1][2], sred[1][3]));
        const float tmn = fminf(fminf(sred[2][0], sred[2][1]), fminf(sred[2][2], sred[2][3]));
        __syncthreads();
        const float av = ts * (1.0f / (float)DD);
        const float denom = kEPS * (tmx - tmn);
        if (denom == 0.0f) {
#pragma unroll
            for (int j = 0; j < 8; j++) r[j] = 1.0f;
        } else {
#pragma unroll
            for (int j = 0; j < 8; j++) {
                float a = (mnew[j] - av) / denom;
                a = fminf(fmaxf(a, -80.0f), 80.0f);
                r[j] = 1.0f / (1.0f + expf(a));
            }
        }
        *(float4*)(W + rowoff)     = *(float4*)(w);
        *(float4*)(W + rowoff + 4) = *(float4*)(w + 4);
        *(float4*)(M + rowoff)     = *(float4*)(mnew);
        *(float4*)(M + rowoff + 4) = *(float4*)(mnew + 4);
        *(float4*)(R + rowoff)     = *(float4*)(r);
        *(float4*)(R + rowoff + 4) = *(float4*)(r + 4);
    } else {
        *(float4*)(r)     = *(const float4*)(R + rowoff);
        *(float4*)(r + 4) = *(const float4*)(R + rowoff + 4);
    }

    if (next) {
        float xn[8];
        *(float4*)(xn)     = *(const float4*)(x_act + xoff);
        *(float4*)(xn + 4) = *(const float4*)(x_act + xoff + 4);
        double pd = 0.0, ps = 0.0;
#pragma unroll
        for (int j = 0; j < 8; j++) {
            const double d  = (double)xn[j] - (double)w[j];
            const double rj = (double)r[j];
            pd += rj * d * d; ps += rj;
        }
        pd = wave_sum_d(pd); ps = wave_sum_d(ps);
        const int wid = tid >> 6, lane = tid & 63;
        if (lane == 0) { sredd[0][wid] = pd; sredd[1][wid] = ps; }
        __syncthreads();
        if (tid == 0) {
            const double td = sredd[0][0] + sredd[0][1] + sredd[0][2] + sredd[0][3];
            const double tr = sredd[1][0] + sredd[1][1] + sredd[1][2] + sredd[1][3];
            const double act = tr / (tr + td + 1e-7);
            const unsigned long long ab = (unsigned long long)__double_as_longlong(act);
            const unsigned long long kk = (ab & ~0xFFFULL) | (unsigned long long)(4095 - n);
            atomicMax(&part_act[(size_t)(n & 63) * 8], kk);
        }
    }
}

extern "C" void kernel_launch(void* const* d_in, const int* in_sizes, int n_in,
                              void* d_out, int out_size, void* d_ws, size_t ws_size,
                              hipStream_t stream) {
    const float*         x   = (const float*)d_in[0];
    const float*         W0  = (const float*)d_in[1];
    float*               M   = (float*)d_in[2];
    float*               R   = (float*)d_in[3];
    const unsigned char* nbb = (const unsigned char*)d_in[5];
    float*               W   = (float*)d_out;

    // ws layout: part (66 slots x 64 x 8 u64) | cnt (64 x 8 x 16 u32) | flag
    unsigned long long* part = (unsigned long long*)d_ws;
    const size_t part_bytes  = (size_t)66 * 64 * 8 * sizeof(unsigned long long); // 270 KB
    unsigned* cnt   = (unsigned*)((char*)d_ws + part_bytes);
    const size_t cnt_bytes = (size_t)BB * 8 * 16 * sizeof(unsigned);             // 32 KB
    unsigned* flagp = (unsigned*)((char*)d_ws + part_bytes + cnt_bytes);

    hipMemsetAsync(d_ws, 0, part_bytes + cnt_bytes + 64, stream);
    detect_nb<<<1, 256, 0, stream>>>(nbb, flagp);

    // persistent path requires all 512 blocks co-resident (2 blocks/CU)
    int occ = 0;
    hipError_t qerr = hipOccupancyMaxActiveBlocksPerMultiprocessor(
        &occ, (const void*)som_persist, 256, 0);
    if (qerr == hipSuccess && occ >= 2) {
        som_persist<<<NBLK, 256, 0, stream>>>(x, W0, M, R, nbb, flagp, W, part, cnt);
        return;
    }

    // ---- fallback: proven 65-dispatch path ----
    hipMemcpyAsync(W, W0, sizeof(float) * (size_t)NN * DD, hipMemcpyDeviceToDevice, stream);
    som_step<<<NN, 256, 0, stream>>>(nullptr, x, W, M, R, nbb, flagp, nullptr, part);
    for (int t = 0; t < BB; t++) {
        const float* xu = x + (size_t)t * DD;
        const float* xa = (t < BB - 1) ? (x + (size_t)(t + 1) * DD) : nullptr;
        const unsigned long long* pu = part + (size_t)t * 64 * 8;
        unsigned long long*       pa = (t < BB - 1) ? (part + (size_t)(t + 1) * 64 * 8) : nullptr;
        som_step<<<NN, 256, 0, stream>>>(xu, xa, W, M, R, nbb, flagp, pu, pa);
    }
}